// Round 5
// baseline (146.370 us; speedup 1.0000x reference)
//
#include <hip/hip_runtime.h>
#include <hip/hip_bf16.h>

typedef __bf16 bf16x8 __attribute__((ext_vector_type(8)));
typedef __bf16 bf16x4v __attribute__((ext_vector_type(4)));
typedef float  f32x4  __attribute__((ext_vector_type(4)));

#define T_TOK   2304
#define HID     1280
#define QKV_N   3840
#define NH      16
#define HD      80
#define NWIN    36

// ---------------------------------------------------------------------------
// async global->LDS 16B copy (wave-uniform LDS base + lane*16 semantics)
// ---------------------------------------------------------------------------
__device__ inline void async_copy16(const __bf16* g, __bf16* l) {
    __builtin_amdgcn_global_load_lds(
        (const __attribute__((address_space(1))) unsigned int*)g,
        (__attribute__((address_space(3))) unsigned int*)l, 16, 0, 0);
}

// ---------------------------------------------------------------------------
// prep: range0 converts x fp32->bf16; range1/2 transpose-convert Wqkv / Wo
// to B^T bf16 layout; range3 precomputes rope cos/sin tables (moves the
// transcendentals off the attention kernel's critical path).
// ---------------------------------------------------------------------------
#define NB_CONV 1440   // 2304*1280 / (256*8)
#define NB_WQKV 1200   // (1280/64) * (3840/64)
#define NB_WO    400   // (1280/64) * (1280/64)
#define NB_ROPE   45   // 2304*40 / (256*8)

__global__ __launch_bounds__(256) void prep_kernel(
    const float* __restrict__ x,    __bf16* __restrict__ Xb,
    const float* __restrict__ Wqkv, __bf16* __restrict__ Wqkv_t,
    const float* __restrict__ Wo,   __bf16* __restrict__ Wo_t,
    const float* __restrict__ rope, float* __restrict__ cosb,
    float* __restrict__ sinb)
{
    __shared__ float t[64][65];
    int b = blockIdx.x;
    const int tid = threadIdx.x;

    if (b < NB_CONV) {
        const int i = (b * 256 + tid) * 8;
        const float4* p = (const float4*)(x + i);
        float4 a0 = p[0], a1 = p[1];
        bf16x8 o;
        o[0] = (__bf16)a0.x; o[1] = (__bf16)a0.y; o[2] = (__bf16)a0.z; o[3] = (__bf16)a0.w;
        o[4] = (__bf16)a1.x; o[5] = (__bf16)a1.y; o[6] = (__bf16)a1.z; o[7] = (__bf16)a1.w;
        *(bf16x8*)(Xb + i) = o;
        return;
    }
    if (b >= NB_CONV + NB_WQKV + NB_WO) {
        // rope table range: 8 angles per thread
        const int i = ((b - NB_CONV - NB_WQKV - NB_WO) * 256 + tid) * 8;
        const float4* p = (const float4*)(rope + i);
        float4 a0 = p[0], a1 = p[1];
        float4 c0, c1, s0, s1;
        __sincosf(a0.x, &s0.x, &c0.x); __sincosf(a0.y, &s0.y, &c0.y);
        __sincosf(a0.z, &s0.z, &c0.z); __sincosf(a0.w, &s0.w, &c0.w);
        __sincosf(a1.x, &s1.x, &c1.x); __sincosf(a1.y, &s1.y, &c1.y);
        __sincosf(a1.z, &s1.z, &c1.z); __sincosf(a1.w, &s1.w, &c1.w);
        *(float4*)(cosb + i) = c0; *(float4*)(cosb + i + 4) = c1;
        *(float4*)(sinb + i) = s0; *(float4*)(sinb + i + 4) = s1;
        return;
    }

    const float* in; __bf16* out; int C, c0, r0;
    const int R = 1280;
    if (b < NB_CONV + NB_WQKV) {
        b -= NB_CONV;
        in = Wqkv; out = Wqkv_t; C = QKV_N;
        c0 = (b % 60) * 64; r0 = (b / 60) * 64;
    } else {
        b -= NB_CONV + NB_WQKV;
        in = Wo; out = Wo_t; C = HID;
        c0 = (b % 20) * 64; r0 = (b / 20) * 64;
    }

    const int lr = tid >> 4;
    const int lc = (tid & 15) * 4;
#pragma unroll
    for (int i = 0; i < 4; ++i) {
        float4 v = *(const float4*)(in + (size_t)(r0 + lr + i * 16) * C + c0 + lc);
        float* d = &t[lr + i * 16][lc];
        d[0] = v.x; d[1] = v.y; d[2] = v.z; d[3] = v.w;
    }
    __syncthreads();
    const int oc  = tid >> 4;
    const int orr = (tid & 15) * 4;
#pragma unroll
    for (int i = 0; i < 4; ++i) {
        const int c = oc + i * 16;
        bf16x4v o;
        o[0] = (__bf16)t[orr + 0][c];
        o[1] = (__bf16)t[orr + 1][c];
        o[2] = (__bf16)t[orr + 2][c];
        o[3] = (__bf16)t[orr + 3][c];
        *(bf16x4v*)(out + (size_t)(c0 + c) * R + r0 + orr) = o;
    }
}

#define SB0()   __builtin_amdgcn_sched_barrier(0)
#define BARR()  __builtin_amdgcn_s_barrier()
#define LGKM0() asm volatile("s_waitcnt lgkmcnt(0)" ::: "memory")
#define VMC(n)  asm volatile("s_waitcnt vmcnt(" #n ")" ::: "memory")

// ---------------------------------------------------------------------------
// QKV GEMM: out[2304,3840] = A[2304,1280] @ Bt[3840,1280]^T + bias.
// BM=192, BN=96, BK=64, 4 waves (2M x 2N, per-wave 96x48), 72 KiB LDS ->
// 2 blocks/CU (independent barriers cover each other's stalls, m114),
// grid 12x40 = 480 blocks (1.875/CU), XCD-swizzled (480 = 8 x 60).
//
// LDS layout per buffer (elements): A 192x64 at [0,12288), B 96x64 at
// [12288,18432). One stage unit = 256 thr x 8 elems = 2048 elems = 32 rows.
//
// Per K-tile t (buf p = t&1), fragment-double-buffered schedule:
//   issue ds_read aHi(t) -> MFMA mh0 (reads in flight under it) ->
//   lgkmcnt(0) -> barrier -> stage tile t+2 (9 units) -> vmcnt(9) (counted;
//   t+1 landed, t+2 in flight) -> barrier -> issue ds_read aLo/bF(t+1) ->
//   MFMA mh1.  2 barriers per K-tile. bF parity-indexed (static).
// LDS XOR swizzle on reads; inverse applied to the global source k-offset
// (global_load_lds dest stays linear).
// ---------------------------------------------------------------------------
__global__ __launch_bounds__(256, 2) void gemm_qkv_kernel(
    const __bf16* __restrict__ A,    // [2304,1280]
    const __bf16* __restrict__ Bt,   // [3840,1280]
    const float* __restrict__ bias,  // [3840]
    __bf16* __restrict__ out)        // [2304,3840]
{
    // 2 bufs x (A 192x64 + B 96x64) bf16 = 72 KiB
    __shared__ __align__(16) __bf16 S[36864];

    const int tid  = threadIdx.x;
    const int wave = tid >> 6, lane = tid & 63;
    const int quad = lane >> 4, l16 = lane & 15;
    const int wr = wave >> 1, wn = wave & 1;

    // XCD-aware bijective swizzle: 480 = 8 XCDs x 60; column-major decompose
    // so each XCD's 60 blocks span ~5 B-panels, each reused 12x in its L2.
    const int lin = blockIdx.y * 40 + blockIdx.x;
    const int swz = (lin & 7) * 60 + (lin >> 3);
    const int m0 = (swz % 12) * 192;
    const int n0 = (swz / 12) * 96;

    // staging: row-in-unit = tid>>3 (32 rows/unit); dest col chunk = tid&7;
    // source k-chunk = (tid&7) ^ (row&7)  (inverse swizzle on global addr)
    const int rloc = tid >> 3;
    const int kcol = ((tid & 7) ^ (rloc & 7)) * 8;

    auto stage_unit = [&](const __bf16* g, int grow, int k0, int eoff) {
        async_copy16(g + (size_t)(grow + rloc) * 1280 + (k0 + kcol),
                     S + eoff + tid * 8);
    };

    // ds-read swizzled chunk offsets (elements) for ksub 0 / 1
    const int chS0 = ((quad) ^ (l16 & 7)) * 8;
    const int chS1 = ((4 + quad) ^ (l16 & 7)) * 8;

    bf16x8 aLo[3][2], aHi[3][2], bFb[2][3][2];
    f32x4 acc[6][3] = {};

#define LDAf(bufo, mh, dst)                                                   \
    {                                                                         \
      const __bf16* baseA_ = S + (bufo) + (wr*96 + (mh)*48 + l16) * 64;       \
      _Pragma("unroll") for (int m_ = 0; m_ < 3; ++m_) {                      \
        dst[m_][0] = *(const bf16x8*)(baseA_ + m_*1024 + chS0);               \
        dst[m_][1] = *(const bf16x8*)(baseA_ + m_*1024 + chS1);               \
      }                                                                       \
    }
#define LDBf(bufo, dst)                                                       \
    {                                                                         \
      const __bf16* baseB_ = S + (bufo) + 12288 + (wn*48 + l16) * 64;         \
      _Pragma("unroll") for (int n_ = 0; n_ < 3; ++n_) {                      \
        dst[n_][0] = *(const bf16x8*)(baseB_ + n_*1024 + chS0);               \
        dst[n_][1] = *(const bf16x8*)(baseB_ + n_*1024 + chS1);               \
      }                                                                       \
    }
#define MMAC(mh, aA, bA)                                                      \
    _Pragma("unroll") for (int m_ = 0; m_ < 3; ++m_)                          \
    _Pragma("unroll") for (int n_ = 0; n_ < 3; ++n_) {                        \
      acc[(mh)*3+m_][n_] = __builtin_amdgcn_mfma_f32_16x16x32_bf16(           \
          aA[m_][0], bA[n_][0], acc[(mh)*3+m_][n_], 0, 0, 0);                 \
      acc[(mh)*3+m_][n_] = __builtin_amdgcn_mfma_f32_16x16x32_bf16(           \
          aA[m_][1], bA[n_][1], acc[(mh)*3+m_][n_], 0, 0, 0);                 \
    }
// one unit = 2048 elements (32 rows x 64 cols); A units 0..5, B units 6..8
#define STAGE9(bufo, k0)                                                      \
    stage_unit(A,  m0,      (k0), (bufo) + 0);                                \
    stage_unit(A,  m0+32,   (k0), (bufo) + 2048);                             \
    stage_unit(A,  m0+64,   (k0), (bufo) + 4096);                             \
    stage_unit(A,  m0+96,   (k0), (bufo) + 6144);                             \
    stage_unit(A,  m0+128,  (k0), (bufo) + 8192);                             \
    stage_unit(A,  m0+160,  (k0), (bufo) + 10240);                            \
    stage_unit(Bt, n0,      (k0), (bufo) + 12288);                            \
    stage_unit(Bt, n0+32,   (k0), (bufo) + 14336);                            \
    stage_unit(Bt, n0+64,   (k0), (bufo) + 16384);

#define TILE(p, kt2)                                                          \
    LDAf((p)*18432, 1, aHi);                                                  \
    __builtin_amdgcn_s_setprio(1); MMAC(0, aLo, bFb[p]);                      \
    __builtin_amdgcn_s_setprio(0);                                            \
    LGKM0(); SB0();                                                           \
    BARR();                                                                   \
    STAGE9((p)*18432, kt2);                                                   \
    VMC(9); SB0();                                                            \
    BARR();                                                                   \
    LDAf((p^1)*18432, 0, aLo); LDBf((p^1)*18432, bFb[p^1]);                   \
    __builtin_amdgcn_s_setprio(1); MMAC(1, aHi, bFb[p]);                      \
    __builtin_amdgcn_s_setprio(0);

    // ---- prologue: stage tiles 0,1; load tile 0's set0 fragments ----
    STAGE9(0, 0);
    STAGE9(18432, 64);
    VMC(9); SB0();     // tile 0's 9 units done; tile 1's stay in flight
    BARR();
    LDAf(0, 0, aLo); LDBf(0, bFb[0]);

    // ---- main loop: K-tiles 0..17 (9 iters x 2 tiles), staging 2..19 ----
    for (int i = 0; i < 9; ++i) {
        const int kt2 = i * 128 + 128;   // k0 of tile 2i+2
        TILE(0, kt2)
        TILE(1, kt2 + 64)
    }

    // ---- epilogue: tiles 18 (buf0) and 19 (buf1), no staging ----
    LDAf(0, 1, aHi);
    __builtin_amdgcn_s_setprio(1); MMAC(0, aLo, bFb[0]);
    __builtin_amdgcn_s_setprio(0);
    LGKM0(); SB0();
    VMC(0); SB0();                     // tile 19's units (issued i=8) done
    BARR();
    LDAf(18432, 0, aLo); LDBf(18432, bFb[1]);
    __builtin_amdgcn_s_setprio(1); MMAC(1, aHi, bFb[0]);
    __builtin_amdgcn_s_setprio(0);
    // tile 19
    LDAf(18432, 1, aHi);
    __builtin_amdgcn_s_setprio(1); MMAC(0, aLo, bFb[1]);
    __builtin_amdgcn_s_setprio(0);
    __builtin_amdgcn_s_setprio(1); MMAC(1, aHi, bFb[1]);
    __builtin_amdgcn_s_setprio(0);

    // ---- C write: row = m0+wr*96+m*16+quad*4+r, col = n0+wn*48+n*16+l16 ----
#pragma unroll
    for (int n_ = 0; n_ < 3; ++n_) {
        const int col = n0 + wn * 48 + n_ * 16 + l16;
        const float bb = bias[col];
#pragma unroll
        for (int m_ = 0; m_ < 6; ++m_) {
            const int row = m0 + wr * 96 + m_ * 16 + quad * 4;
#pragma unroll
            for (int r = 0; r < 4; ++r)
                out[(size_t)(row + r) * QKV_N + col] = (__bf16)(acc[m_][n_][r] + bb);
        }
    }

#undef LDAf
#undef LDBf
#undef MMAC
#undef STAGE9
#undef TILE
}

// ---------------------------------------------------------------------------
// Overlapped pipeline for the Wo projection: out[2304,1280] (fp32) =
// A[2304,1280] @ Bt[1280,1280]^T + bias.  BM=192, BN=64, BK=64, 4 waves
// (2M x 2N, per-wave 96x32), 64 KiB LDS -> 2 blocks/CU, grid 20x12 = 240
// blocks, XCD-swizzled. Same schedule; 8 stage units/tile -> vmcnt(8).
// ---------------------------------------------------------------------------
__global__ __launch_bounds__(256, 2) void gemm_wo_kernel(
    const __bf16* __restrict__ A,    // [2304,1280]
    const __bf16* __restrict__ Bt,   // [1280,1280]
    const float* __restrict__ bias,  // [1280]
    float* __restrict__ out)         // [2304,1280]
{
    // 2 bufs x (A 192x64 + B 64x64) bf16 = 64 KiB
    __shared__ __align__(16) __bf16 S[32768];

    const int tid  = threadIdx.x;
    const int wave = tid >> 6, lane = tid & 63;
    const int quad = lane >> 4, l16 = lane & 15;
    const int wr = wave >> 1, wn = wave & 1;

    const int lin = blockIdx.y * 20 + blockIdx.x;
    const int swz = (lin & 7) * 30 + (lin >> 3);
    const int m0 = (swz % 12) * 192;
    const int n0 = (swz / 12) * 64;

    // staging: 256 threads -> 32 rows/unit, 8 chunks/row
    const int rloc = tid >> 3;
    const int kcol = ((tid & 7) ^ (rloc & 7)) * 8;

    auto stage_unit = [&](const __bf16* g, int grow, int k0, int chunk0) {
        async_copy16(g + (size_t)(grow + rloc) * 1280 + (k0 + kcol),
                     S + (chunk0 + tid) * 8);
    };

    const int chS0 = ((quad) ^ (l16 & 7)) * 8;
    const int chS1 = ((4 + quad) ^ (l16 & 7)) * 8;

    bf16x8 aLo[3][2], aHi[3][2], bFb[2][2][2];
    f32x4 acc[6][2] = {};

#define LDAf2(buf, mh, dst)                                                   \
    {                                                                         \
      const __bf16* baseA_ = S + (buf)*16384 + (wr*96 + (mh)*48 + l16) * 64;  \
      _Pragma("unroll") for (int m_ = 0; m_ < 3; ++m_) {                      \
        dst[m_][0] = *(const bf16x8*)(baseA_ + m_*1024 + chS0);               \
        dst[m_][1] = *(const bf16x8*)(baseA_ + m_*1024 + chS1);               \
      }                                                                       \
    }
#define LDBf2(buf, dst)                                                       \
    {                                                                         \
      const __bf16* baseB_ = S + (buf)*16384 + 12288 + (wn*32 + l16) * 64;    \
      _Pragma("unroll") for (int n_ = 0; n_ < 2; ++n_) {                      \
        dst[n_][0] = *(const bf16x8*)(baseB_ + n_*1024 + chS0);               \
        dst[n_][1] = *(const bf16x8*)(baseB_ + n_*1024 + chS1);               \
      }                                                                       \
    }
#define MMAC2(mh, aA, bA)                                                     \
    _Pragma("unroll") for (int m_ = 0; m_ < 3; ++m_)                          \
    _Pragma("unroll") for (int n_ = 0; n_ < 2; ++n_) {                        \
      acc[(mh)*3+m_][n_] = __builtin_amdgcn_mfma_f32_16x16x32_bf16(           \
          aA[m_][0], bA[n_][0], acc[(mh)*3+m_][n_], 0, 0, 0);                 \
      acc[(mh)*3+m_][n_] = __builtin_amdgcn_mfma_f32_16x16x32_bf16(           \
          aA[m_][1], bA[n_][1], acc[(mh)*3+m_][n_], 0, 0, 0);                 \
    }
#define STAGE8(buf, k0)                                                       \
    stage_unit(A,  m0,      (k0), (buf)*2048 + 0);                            \
    stage_unit(A,  m0+32,   (k0), (buf)*2048 + 256);                          \
    stage_unit(A,  m0+64,   (k0), (buf)*2048 + 512);                          \
    stage_unit(A,  m0+96,   (k0), (buf)*2048 + 768);                          \
    stage_unit(A,  m0+128,  (k0), (buf)*2048 + 1024);                         \
    stage_unit(A,  m0+160,  (k0), (buf)*2048 + 1280);                         \
    stage_unit(Bt, n0,      (k0), (buf)*2048 + 1536);                         \
    stage_unit(Bt, n0+32,   (k0), (buf)*2048 + 1792);

#define TILE2(p, kt2)                                                         \
    LDAf2(p, 1, aHi);                                                         \
    __builtin_amdgcn_s_setprio(1); MMAC2(0, aLo, bFb[p]);                     \
    __builtin_amdgcn_s_setprio(0);                                            \
    LGKM0(); SB0();                                                           \
    BARR();                                                                   \
    STAGE8(p, kt2);                                                           \
    VMC(8); SB0();                                                            \
    BARR();                                                                   \
    LDAf2(p^1, 0, aLo); LDBf2(p^1, bFb[p^1]);                                 \
    __builtin_amdgcn_s_setprio(1); MMAC2(1, aHi, bFb[p]);                     \
    __builtin_amdgcn_s_setprio(0);

    // ---- prologue ----
    STAGE8(0, 0);
    STAGE8(1, 64);
    VMC(8); SB0();
    BARR();
    LDAf2(0, 0, aLo); LDBf2(0, bFb[0]);

    // ---- main loop: K-tiles 0..17, staging 2..19 ----
    for (int i = 0; i < 9; ++i) {
        const int kt2 = i * 128 + 128;
        TILE2(0, kt2)
        TILE2(1, kt2 + 64)
    }

    // ---- epilogue: tiles 18 (buf0), 19 (buf1) ----
    LDAf2(0, 1, aHi);
    __builtin_amdgcn_s_setprio(1); MMAC2(0, aLo, bFb[0]);
    __builtin_amdgcn_s_setprio(0);
    LGKM0(); SB0();
    VMC(0); SB0();
    BARR();
    LDAf2(1, 0, aLo); LDBf2(1, bFb[1]);
    __builtin_amdgcn_s_setprio(1); MMAC2(1, aHi, bFb[0]);
    __builtin_amdgcn_s_setprio(0);
    LDAf2(1, 1, aHi);
    __builtin_amdgcn_s_setprio(1); MMAC2(0, aLo, bFb[1]);
    __builtin_amdgcn_s_setprio(0);
    __builtin_amdgcn_s_setprio(1); MMAC2(1, aHi, bFb[1]);
    __builtin_amdgcn_s_setprio(0);

    // ---- C write ----
#pragma unroll
    for (int n_ = 0; n_ < 2; ++n_) {
        const int col = n0 + wn * 32 + n_ * 16 + l16;
        const float bb = bias[col];
#pragma unroll
        for (int m_ = 0; m_ < 6; ++m_) {
            const int row = m0 + wr * 96 + m_ * 16 + quad * 4;
#pragma unroll
            for (int r = 0; r < 4; ++r)
                out[(size_t)(row + r) * HID + col] = acc[m_][n_][r] + bb;
        }
    }

#undef LDAf2
#undef LDBf2
#undef MMAC2
#undef STAGE8
#undef TILE2
}

// ---------------------------------------------------------------------------
// Fused rotary + windowed attention. One block per (window, head).
// Rope cos/sin come from precomputed tables (prep range 3).
// ---------------------------------------------------------------------------
__global__ __launch_bounds__(256) void attn_win_kernel(
    const __bf16* __restrict__ qkv,   // [2304, 3840]
    const float* __restrict__ cosb,   // [2304, 40]
    const float* __restrict__ sinb,   // [2304, 40]
    __bf16* __restrict__ attn_out)    // [2304, 1280]
{
    const int w = blockIdx.x;
    const int h = blockIdx.y;

    __shared__ __bf16 Qs[64 * 104];  // [t][d], d padded 80->96, stride 104
    __shared__ __bf16 Ks[64 * 104];
    __shared__ __bf16 Vt[80 * 72];   // [d][t], stride 72
    __shared__ __bf16 Ps[64 * 72];   // probs, stride 72

    const int tid = threadIdx.x;

    for (int u = tid; u < 320; u += 256) {
        const int t = u & 63;
        const int p = u >> 6;
        const int tg = w * 64 + t;
        const size_t base = (size_t)tg * QKV_N + h * HD;
        const int d0 = p * 8;

        bf16x8 qa = *(const bf16x8*)(qkv + base + d0);
        bf16x8 qb = *(const bf16x8*)(qkv + base + d0 + 40);
        bf16x8 ka = *(const bf16x8*)(qkv + base + HID + d0);
        bf16x8 kb = *(const bf16x8*)(qkv + base + HID + d0 + 40);
        bf16x8 va = *(const bf16x8*)(qkv + base + 2 * HID + d0);
        bf16x8 vb = *(const bf16x8*)(qkv + base + 2 * HID + d0 + 40);
        float4 c0 = *(const float4*)(cosb + tg * 40 + d0);
        float4 c1 = *(const float4*)(cosb + tg * 40 + d0 + 4);
        float4 s0 = *(const float4*)(sinb + tg * 40 + d0);
        float4 s1 = *(const float4*)(sinb + tg * 40 + d0 + 4);
        const float cs[8] = {c0.x, c0.y, c0.z, c0.w, c1.x, c1.y, c1.z, c1.w};
        const float sn[8] = {s0.x, s0.y, s0.z, s0.w, s1.x, s1.y, s1.z, s1.w};

        bf16x8 qoa, qob, koa, kob;
#pragma unroll
        for (int j = 0; j < 8; ++j) {
            const float q0 = (float)qa[j], q1 = (float)qb[j];
            const float k0 = (float)ka[j], k1 = (float)kb[j];
            qoa[j] = (__bf16)(q0 * cs[j] - q1 * sn[j]);
            qob[j] = (__bf16)(q0 * sn[j] + q1 * cs[j]);
            koa[j] = (__bf16)(k0 * cs[j] - k1 * sn[j]);
            kob[j] = (__bf16)(k0 * sn[j] + k1 * cs[j]);
        }
        *(bf16x8*)(Qs + t * 104 + d0)      = qoa;
        *(bf16x8*)(Qs + t * 104 + d0 + 40) = qob;
        *(bf16x8*)(Ks + t * 104 + d0)      = koa;
        *(bf16x8*)(Ks + t * 104 + d0 + 40) = kob;
#pragma unroll
        for (int j = 0; j < 8; ++j) {
            Vt[(d0 + j) * 72 + t]      = va[j];
            Vt[(d0 + j + 40) * 72 + t] = vb[j];
        }
    }
    for (int idx = tid; idx < 64 * 16; idx += 256) {
        const int t = idx >> 4, d = 80 + (idx & 15);
        Qs[t * 104 + d] = (__bf16)0.f;
        Ks[t * 104 + d] = (__bf16)0.f;
    }
    __syncthreads();

    const int wave = tid >> 6, lane = tid & 63;
    const int quad = lane >> 4, l16 = lane & 15;

    // ---- S = Q K^T ----
    f32x4 sacc[4] = {};
#pragma unroll
    for (int k0 = 0; k0 < 96; k0 += 32) {
        bf16x8 af = *(const bf16x8*)(Qs + (wave * 16 + l16) * 104 + k0 + quad * 8);
#pragma unroll
        for (int ct = 0; ct < 4; ++ct) {
            bf16x8 bf = *(const bf16x8*)(Ks + (ct * 16 + l16) * 104 + k0 + quad * 8);
            sacc[ct] = __builtin_amdgcn_mfma_f32_16x16x32_bf16(af, bf, sacc[ct], 0, 0, 0);
        }
    }

    // ---- in-register softmax over the 16-lane row group ----
    const float scale = 0.11180339887498948f;  // 1/sqrt(80)
#pragma unroll
    for (int r = 0; r < 4; ++r) {
        float m = -1e30f;
#pragma unroll
        for (int ct = 0; ct < 4; ++ct) {
            sacc[ct][r] *= scale;
            m = fmaxf(m, sacc[ct][r]);
        }
        m = fmaxf(m, __shfl_xor(m, 1));
        m = fmaxf(m, __shfl_xor(m, 2));
        m = fmaxf(m, __shfl_xor(m, 4));
        m = fmaxf(m, __shfl_xor(m, 8));
        float e[4], s = 0.f;
#pragma unroll
        for (int ct = 0; ct < 4; ++ct) {
            e[ct] = __expf(sacc[ct][r] - m);
            s += e[ct];
        }
        s += __shfl_xor(s, 1);
        s += __shfl_xor(s, 2);
        s += __shfl_xor(s, 4);
        s += __shfl_xor(s, 8);
        const float inv = 1.0f / s;
        const int row = wave * 16 + quad * 4 + r;
#pragma unroll
        for (int ct = 0; ct < 4; ++ct)
            Ps[row * 72 + ct * 16 + l16] = (__bf16)(e[ct] * inv);
    }
    __syncthreads();

    // ---- O = P V ----
    f32x4 oacc[5] = {};
#pragma unroll
    for (int k0 = 0; k0 < 64; k0 += 32) {
        bf16x8 af = *(const bf16x8*)(Ps + (wave * 16 + l16) * 72 + k0 + quad * 8);
#pragma unroll
        for (int nt = 0; nt < 5; ++nt) {
            bf16x8 bf = *(const bf16x8*)(Vt + (nt * 16 + l16) * 72 + k0 + quad * 8);
            oacc[nt] = __builtin_amdgcn_mfma_f32_16x16x32_bf16(af, bf, oacc[nt], 0, 0, 0);
        }
    }
#pragma unroll
    for (int nt = 0; nt < 5; ++nt) {
        const int d = nt * 16 + l16;
#pragma unroll
        for (int r = 0; r < 4; ++r) {
            const int t = w * 64 + wave * 16 + quad * 4 + r;
            attn_out[(size_t)t * HID + h * HD + d] = (__bf16)oacc[nt][r];
        }
    }
}

// ---------------------------------------------------------------------------
extern "C" void kernel_launch(void* const* d_in, const int* in_sizes, int n_in,
                              void* d_out, int out_size, void* d_ws, size_t ws_size,
                              hipStream_t stream) {
    const float* x    = (const float*)d_in[0];
    const float* rope = (const float*)d_in[1];
    // d_in[2] = cu_window_seqlens (statically: 36 full 64-token windows)
    const float* Wqkv = (const float*)d_in[3];
    const float* bqkv = (const float*)d_in[4];
    const float* Wo   = (const float*)d_in[5];
    const float* bo   = (const float*)d_in[6];
    float* out = (float*)d_out;

    char* ws = (char*)d_ws;
    const size_t szXb = (size_t)T_TOK * HID * 2;
    const size_t szWq = (size_t)QKV_N * HID * 2;
    const size_t szWo = (size_t)HID * HID * 2;
    const size_t szQK = (size_t)T_TOK * QKV_N * 2;
    __bf16* Xb      = (__bf16*)ws;
    __bf16* Wqkv_t  = (__bf16*)(ws + szXb);
    __bf16* Wo_t    = (__bf16*)(ws + szXb + szWq);
    __bf16* qkv_bf  = (__bf16*)(ws + szXb + szWq + szWo);
    float*  cosb    = (float*)(ws + szXb + szWq + szWo + szQK);
    float*  sinb    = cosb + (size_t)T_TOK * 40;
    __bf16* attn_bf = (__bf16*)ws;   // aliases Xb (dead after gemm_qkv)

    prep_kernel<<<NB_CONV + NB_WQKV + NB_WO + NB_ROPE, 256, 0, stream>>>(
        x, Xb, Wqkv, Wqkv_t, Wo, Wo_t, rope, cosb, sinb);

    // 192x96x64 pipeline: 480 blocks, 2 blocks/CU
    gemm_qkv_kernel<<<dim3(QKV_N / 96, T_TOK / 192), 256, 0, stream>>>(
        Xb, Wqkv_t, bqkv, qkv_bf);

    attn_win_kernel<<<dim3(NWIN, NH), 256, 0, stream>>>(qkv_bf, cosb, sinb, attn_bf);

    // 192x64x64 pipeline: 240 blocks, 2 blocks/CU
    gemm_wo_kernel<<<dim3(HID / 64, T_TOK / 192), 256, 0, stream>>>(
        attn_bf, Wo_t, bo, out);
}

// Round 6
// 141.205 us; speedup vs baseline: 1.0366x; 1.0366x over previous
//
#include <hip/hip_runtime.h>
#include <hip/hip_bf16.h>

typedef __bf16 bf16x8 __attribute__((ext_vector_type(8)));
typedef __bf16 bf16x4v __attribute__((ext_vector_type(4)));
typedef float  f32x4  __attribute__((ext_vector_type(4)));

#define T_TOK   2304
#define HID     1280
#define QKV_N   3840
#define NH      16
#define HD      80
#define NWIN    36

// ---------------------------------------------------------------------------
// async global->LDS 16B copy (wave-uniform LDS base + lane*16 semantics)
// ---------------------------------------------------------------------------
__device__ inline void async_copy16(const __bf16* g, __bf16* l) {
    __builtin_amdgcn_global_load_lds(
        (const __attribute__((address_space(1))) unsigned int*)g,
        (__attribute__((address_space(3))) unsigned int*)l, 16, 0, 0);
}

// ---------------------------------------------------------------------------
// prep: range0 converts x fp32->bf16; range1/2 transpose-convert Wqkv / Wo
// to B^T bf16 layout; range3 precomputes rope cos/sin tables.
// ---------------------------------------------------------------------------
#define NB_CONV 1440   // 2304*1280 / (256*8)
#define NB_WQKV 1200   // (1280/64) * (3840/64)
#define NB_WO    400   // (1280/64) * (1280/64)
#define NB_ROPE   45   // 2304*40 / (256*8)

__global__ __launch_bounds__(256) void prep_kernel(
    const float* __restrict__ x,    __bf16* __restrict__ Xb,
    const float* __restrict__ Wqkv, __bf16* __restrict__ Wqkv_t,
    const float* __restrict__ Wo,   __bf16* __restrict__ Wo_t,
    const float* __restrict__ rope, float* __restrict__ cosb,
    float* __restrict__ sinb)
{
    __shared__ float t[64][65];
    int b = blockIdx.x;
    const int tid = threadIdx.x;

    if (b < NB_CONV) {
        const int i = (b * 256 + tid) * 8;
        const float4* p = (const float4*)(x + i);
        float4 a0 = p[0], a1 = p[1];
        bf16x8 o;
        o[0] = (__bf16)a0.x; o[1] = (__bf16)a0.y; o[2] = (__bf16)a0.z; o[3] = (__bf16)a0.w;
        o[4] = (__bf16)a1.x; o[5] = (__bf16)a1.y; o[6] = (__bf16)a1.z; o[7] = (__bf16)a1.w;
        *(bf16x8*)(Xb + i) = o;
        return;
    }
    if (b >= NB_CONV + NB_WQKV + NB_WO) {
        const int i = ((b - NB_CONV - NB_WQKV - NB_WO) * 256 + tid) * 8;
        const float4* p = (const float4*)(rope + i);
        float4 a0 = p[0], a1 = p[1];
        float4 c0, c1, s0, s1;
        __sincosf(a0.x, &s0.x, &c0.x); __sincosf(a0.y, &s0.y, &c0.y);
        __sincosf(a0.z, &s0.z, &c0.z); __sincosf(a0.w, &s0.w, &c0.w);
        __sincosf(a1.x, &s1.x, &c1.x); __sincosf(a1.y, &s1.y, &c1.y);
        __sincosf(a1.z, &s1.z, &c1.z); __sincosf(a1.w, &s1.w, &c1.w);
        *(float4*)(cosb + i) = c0; *(float4*)(cosb + i + 4) = c1;
        *(float4*)(sinb + i) = s0; *(float4*)(sinb + i + 4) = s1;
        return;
    }

    const float* in; __bf16* out; int C, c0, r0;
    const int R = 1280;
    if (b < NB_CONV + NB_WQKV) {
        b -= NB_CONV;
        in = Wqkv; out = Wqkv_t; C = QKV_N;
        c0 = (b % 60) * 64; r0 = (b / 60) * 64;
    } else {
        b -= NB_CONV + NB_WQKV;
        in = Wo; out = Wo_t; C = HID;
        c0 = (b % 20) * 64; r0 = (b / 20) * 64;
    }

    const int lr = tid >> 4;
    const int lc = (tid & 15) * 4;
#pragma unroll
    for (int i = 0; i < 4; ++i) {
        float4 v = *(const float4*)(in + (size_t)(r0 + lr + i * 16) * C + c0 + lc);
        float* d = &t[lr + i * 16][lc];
        d[0] = v.x; d[1] = v.y; d[2] = v.z; d[3] = v.w;
    }
    __syncthreads();
    const int oc  = tid >> 4;
    const int orr = (tid & 15) * 4;
#pragma unroll
    for (int i = 0; i < 4; ++i) {
        const int c = oc + i * 16;
        bf16x4v o;
        o[0] = (__bf16)t[orr + 0][c];
        o[1] = (__bf16)t[orr + 1][c];
        o[2] = (__bf16)t[orr + 2][c];
        o[3] = (__bf16)t[orr + 3][c];
        *(bf16x4v*)(out + (size_t)(c0 + c) * R + r0 + orr) = o;
    }
}

#define SB0()   __builtin_amdgcn_sched_barrier(0)
#define BARR()  __builtin_amdgcn_s_barrier()
#define VMC(n)  asm volatile("s_waitcnt vmcnt(" #n ")" ::: "memory")

// ---------------------------------------------------------------------------
// QKV GEMM, 3-buffer rotation: out[2304,3840] = A[2304,1280] @
// Bt[3840,1280]^T + bias.  BM=BN=192, BK=64, 8 waves (2M x 4N, per-wave
// 96x48), grid 20x12 = 240 blocks, XCD-swizzled, 144 KiB LDS (3 bufs).
//
// Tile t: reads buf r=t%3 (and prefetches fragments for t+1 from rn=(t+1)%3);
// stages tile t+2 into buf w=(t+2)%3 - a buffer NOBODY reads this tile, so
// no lgkmcnt(0) drain is needed: all reads of buf w (tile t-1's fragments)
// were consumed by tile t-1's MFMAs (compiler-enforced waits) before this
// tile's barrier. ONE barrier per tile; STAGE issued right after it ->
// ~1.7-tile prefetch distance. vmcnt(6) counted (this tile's 6 units in
// flight; waits only for tile t+1's units), placed after MMAC0 so aHi reads
// + 18 MFMA cover the latency. bF parity-indexed (q=t&1); loop unrolled 6
// (lcm of buf period 3 and parity 2).
// LDS XOR swizzle on reads; inverse applied to the global source k-offset.
// ---------------------------------------------------------------------------
__global__ __launch_bounds__(512, 2) void gemm192_kernel(
    const __bf16* __restrict__ A,    // [2304,1280]
    const __bf16* __restrict__ Bt,   // [3840,1280]
    const float* __restrict__ bias,  // [3840]
    __bf16* __restrict__ out)        // [2304,3840]
{
    // 3 bufs x (A 192x64 + B 192x64) bf16 = 144 KiB; buf stride 24576 elems
    __shared__ __align__(16) __bf16 S[73728];

    const int tid  = threadIdx.x;
    const int wave = tid >> 6, lane = tid & 63;
    const int quad = lane >> 4, l16 = lane & 15;
    const int wr = wave >> 2, wn = wave & 3;

    // XCD-aware bijective swizzle: 240 = 8 XCDs x 30
    const int lin = blockIdx.y * 20 + blockIdx.x;
    const int swz = (lin & 7) * 30 + (lin >> 3);
    const int m0 = (swz % 12) * 192;
    const int n0 = (swz / 12) * 192;

    // staging: row-in-unit = tid>>3 (64 rows/unit); dest col chunk = tid&7;
    // source k-chunk = (tid&7) ^ (row&7)  (inverse swizzle on global addr)
    const int rloc = tid >> 3;
    const int kcol = ((tid & 7) ^ (rloc & 7)) * 8;

    auto stage_unit = [&](const __bf16* g, int grow, int k0, int chunk0) {
        async_copy16(g + (size_t)(grow + rloc) * 1280 + (k0 + kcol),
                     S + (chunk0 + tid) * 8);
    };

    // ds-read swizzled chunk offsets (elements) for ksub 0 / 1
    const int chS0 = ((quad) ^ (l16 & 7)) * 8;
    const int chS1 = ((4 + quad) ^ (l16 & 7)) * 8;

    bf16x8 aLo[3][2], aHi[3][2], bFb[2][3][2];
    f32x4 acc[6][3] = {};

#define LDAf(buf, mh, dst)                                                    \
    {                                                                         \
      const __bf16* baseA_ = S + (buf)*24576 + (wr*96 + (mh)*48 + l16) * 64;  \
      _Pragma("unroll") for (int m_ = 0; m_ < 3; ++m_) {                      \
        dst[m_][0] = *(const bf16x8*)(baseA_ + m_*1024 + chS0);               \
        dst[m_][1] = *(const bf16x8*)(baseA_ + m_*1024 + chS1);               \
      }                                                                       \
    }
#define LDBf(buf, dst)                                                        \
    {                                                                         \
      const __bf16* baseB_ = S + (buf)*24576 + 12288 + (wn*48 + l16) * 64;    \
      _Pragma("unroll") for (int n_ = 0; n_ < 3; ++n_) {                      \
        dst[n_][0] = *(const bf16x8*)(baseB_ + n_*1024 + chS0);               \
        dst[n_][1] = *(const bf16x8*)(baseB_ + n_*1024 + chS1);               \
      }                                                                       \
    }
#define MMAC(mh, aA, bA)                                                      \
    _Pragma("unroll") for (int m_ = 0; m_ < 3; ++m_)                          \
    _Pragma("unroll") for (int n_ = 0; n_ < 3; ++n_) {                        \
      acc[(mh)*3+m_][n_] = __builtin_amdgcn_mfma_f32_16x16x32_bf16(           \
          aA[m_][0], bA[n_][0], acc[(mh)*3+m_][n_], 0, 0, 0);                 \
      acc[(mh)*3+m_][n_] = __builtin_amdgcn_mfma_f32_16x16x32_bf16(           \
          aA[m_][1], bA[n_][1], acc[(mh)*3+m_][n_], 0, 0, 0);                 \
    }
// one unit = 512 thr x 8 elems = 4096 elems = 64 rows; A units 0-2, B 3-5
#define STAGE6(buf, k0)                                                       \
    stage_unit(A,  m0,      (k0), (buf)*3072 + 0);                            \
    stage_unit(A,  m0+64,   (k0), (buf)*3072 + 512);                          \
    stage_unit(A,  m0+128,  (k0), (buf)*3072 + 1024);                         \
    stage_unit(Bt, n0,      (k0), (buf)*3072 + 1536);                         \
    stage_unit(Bt, n0+64,   (k0), (buf)*3072 + 2048);                         \
    stage_unit(Bt, n0+128,  (k0), (buf)*3072 + 2560);

// tile t: r=t%3, w=(t+2)%3, q=t&1, rn=(t+1)%3
#define TILE3(r, w, q, rn, kt2)                                               \
    BARR();                                                                   \
    STAGE6(w, kt2);                                                           \
    LDAf(r, 1, aHi);                                                          \
    __builtin_amdgcn_s_setprio(1); MMAC(0, aLo, bFb[q]);                      \
    __builtin_amdgcn_s_setprio(0);                                            \
    VMC(6); SB0();                                                            \
    LDAf(rn, 0, aLo); LDBf(rn, bFb[q^1]);                                     \
    __builtin_amdgcn_s_setprio(1); MMAC(1, aHi, bFb[q]);                      \
    __builtin_amdgcn_s_setprio(0);

    // ---- prologue: stage tiles 0,1 into bufs 0,1; fragments for tile 0 ----
    STAGE6(0, 0);
    STAGE6(1, 64);
    VMC(6); SB0();     // tile 0's 6 units done; tile 1's stay in flight
    BARR();
    LDAf(0, 0, aLo); LDBf(0, bFb[0]);

    // ---- main loop: tiles 0..17 (3 iters x 6 tiles), staging 2..19 ----
    for (int i = 0; i < 3; ++i) {
        const int kb = i * 384;
        TILE3(0, 2, 0, 1, kb + 128)
        TILE3(1, 0, 1, 2, kb + 192)
        TILE3(2, 1, 0, 0, kb + 256)
        TILE3(0, 2, 1, 1, kb + 320)
        TILE3(1, 0, 0, 2, kb + 384)
        TILE3(2, 1, 1, 0, kb + 448)
    }

    // ---- epilogue: tiles 18 (buf0,q0) and 19 (buf1,q1), no staging ----
    BARR();
    LDAf(0, 1, aHi);
    __builtin_amdgcn_s_setprio(1); MMAC(0, aLo, bFb[0]);
    __builtin_amdgcn_s_setprio(0);
    VMC(0); SB0();                     // tile 19's units (staged at t=17) done
    LDAf(1, 0, aLo); LDBf(1, bFb[1]);
    __builtin_amdgcn_s_setprio(1); MMAC(1, aHi, bFb[0]);
    __builtin_amdgcn_s_setprio(0);
    LDAf(1, 1, aHi);
    __builtin_amdgcn_s_setprio(1); MMAC(0, aLo, bFb[1]);
    __builtin_amdgcn_s_setprio(0);
    __builtin_amdgcn_s_setprio(1); MMAC(1, aHi, bFb[1]);
    __builtin_amdgcn_s_setprio(0);

    // ---- C write: row = m0+wr*96+m*16+quad*4+r, col = n0+wn*48+n*16+l16 ----
#pragma unroll
    for (int n_ = 0; n_ < 3; ++n_) {
        const int col = n0 + wn * 48 + n_ * 16 + l16;
        const float bb = bias[col];
#pragma unroll
        for (int m_ = 0; m_ < 6; ++m_) {
            const int row = m0 + wr * 96 + m_ * 16 + quad * 4;
#pragma unroll
            for (int r = 0; r < 4; ++r)
                out[(size_t)(row + r) * QKV_N + col] = (__bf16)(acc[m_][n_][r] + bb);
        }
    }

#undef LDAf
#undef LDBf
#undef MMAC
#undef STAGE6
#undef TILE3
}

#define LGKM0() asm volatile("s_waitcnt lgkmcnt(0)" ::: "memory")

// ---------------------------------------------------------------------------
// Overlapped pipeline for the Wo projection: out[2304,1280] (fp32) =
// A[2304,1280] @ Bt[1280,1280]^T + bias.  BM=192, BN=64, BK=64, 4 waves
// (2M x 2N, per-wave 96x32), 64 KiB LDS -> 2 blocks/CU, grid 20x12 = 240
// blocks, XCD-swizzled. 8 stage units/tile -> vmcnt(8).
// ---------------------------------------------------------------------------
__global__ __launch_bounds__(256, 2) void gemm_wo_kernel(
    const __bf16* __restrict__ A,    // [2304,1280]
    const __bf16* __restrict__ Bt,   // [1280,1280]
    const float* __restrict__ bias,  // [1280]
    float* __restrict__ out)         // [2304,1280]
{
    // 2 bufs x (A 192x64 + B 64x64) bf16 = 64 KiB
    __shared__ __align__(16) __bf16 S[32768];

    const int tid  = threadIdx.x;
    const int wave = tid >> 6, lane = tid & 63;
    const int quad = lane >> 4, l16 = lane & 15;
    const int wr = wave >> 1, wn = wave & 1;

    const int lin = blockIdx.y * 20 + blockIdx.x;
    const int swz = (lin & 7) * 30 + (lin >> 3);
    const int m0 = (swz % 12) * 192;
    const int n0 = (swz / 12) * 64;

    // staging: 256 threads -> 32 rows/unit, 8 chunks/row
    const int rloc = tid >> 3;
    const int kcol = ((tid & 7) ^ (rloc & 7)) * 8;

    auto stage_unit = [&](const __bf16* g, int grow, int k0, int chunk0) {
        async_copy16(g + (size_t)(grow + rloc) * 1280 + (k0 + kcol),
                     S + (chunk0 + tid) * 8);
    };

    const int chS0 = ((quad) ^ (l16 & 7)) * 8;
    const int chS1 = ((4 + quad) ^ (l16 & 7)) * 8;

    bf16x8 aLo[3][2], aHi[3][2], bFb[2][2][2];
    f32x4 acc[6][2] = {};

#define LDAf2(buf, mh, dst)                                                   \
    {                                                                         \
      const __bf16* baseA_ = S + (buf)*16384 + (wr*96 + (mh)*48 + l16) * 64;  \
      _Pragma("unroll") for (int m_ = 0; m_ < 3; ++m_) {                      \
        dst[m_][0] = *(const bf16x8*)(baseA_ + m_*1024 + chS0);               \
        dst[m_][1] = *(const bf16x8*)(baseA_ + m_*1024 + chS1);               \
      }                                                                       \
    }
#define LDBf2(buf, dst)                                                       \
    {                                                                         \
      const __bf16* baseB_ = S + (buf)*16384 + 12288 + (wn*32 + l16) * 64;    \
      _Pragma("unroll") for (int n_ = 0; n_ < 2; ++n_) {                      \
        dst[n_][0] = *(const bf16x8*)(baseB_ + n_*1024 + chS0);               \
        dst[n_][1] = *(const bf16x8*)(baseB_ + n_*1024 + chS1);               \
      }                                                                       \
    }
#define MMAC2(mh, aA, bA)                                                     \
    _Pragma("unroll") for (int m_ = 0; m_ < 3; ++m_)                          \
    _Pragma("unroll") for (int n_ = 0; n_ < 2; ++n_) {                        \
      acc[(mh)*3+m_][n_] = __builtin_amdgcn_mfma_f32_16x16x32_bf16(           \
          aA[m_][0], bA[n_][0], acc[(mh)*3+m_][n_], 0, 0, 0);                 \
      acc[(mh)*3+m_][n_] = __builtin_amdgcn_mfma_f32_16x16x32_bf16(           \
          aA[m_][1], bA[n_][1], acc[(mh)*3+m_][n_], 0, 0, 0);                 \
    }
#define STAGE8(buf, k0)                                                       \
    stage_unit(A,  m0,      (k0), (buf)*2048 + 0);                            \
    stage_unit(A,  m0+32,   (k0), (buf)*2048 + 256);                          \
    stage_unit(A,  m0+64,   (k0), (buf)*2048 + 512);                          \
    stage_unit(A,  m0+96,   (k0), (buf)*2048 + 768);                          \
    stage_unit(A,  m0+128,  (k0), (buf)*2048 + 1024);                         \
    stage_unit(A,  m0+160,  (k0), (buf)*2048 + 1280);                         \
    stage_unit(Bt, n0,      (k0), (buf)*2048 + 1536);                         \
    stage_unit(Bt, n0+32,   (k0), (buf)*2048 + 1792);

#define TILE2(p, kt2)                                                         \
    LDAf2(p, 1, aHi);                                                         \
    __builtin_amdgcn_s_setprio(1); MMAC2(0, aLo, bFb[p]);                     \
    __builtin_amdgcn_s_setprio(0);                                            \
    LGKM0(); SB0();                                                           \
    BARR();                                                                   \
    STAGE8(p, kt2);                                                           \
    VMC(8); SB0();                                                            \
    BARR();                                                                   \
    LDAf2(p^1, 0, aLo); LDBf2(p^1, bFb[p^1]);                                 \
    __builtin_amdgcn_s_setprio(1); MMAC2(1, aHi, bFb[p]);                     \
    __builtin_amdgcn_s_setprio(0);

    // ---- prologue ----
    STAGE8(0, 0);
    STAGE8(1, 64);
    VMC(8); SB0();
    BARR();
    LDAf2(0, 0, aLo); LDBf2(0, bFb[0]);

    // ---- main loop: K-tiles 0..17, staging 2..19 ----
    for (int i = 0; i < 9; ++i) {
        const int kt2 = i * 128 + 128;
        TILE2(0, kt2)
        TILE2(1, kt2 + 64)
    }

    // ---- epilogue: tiles 18 (buf0), 19 (buf1) ----
    LDAf2(0, 1, aHi);
    __builtin_amdgcn_s_setprio(1); MMAC2(0, aLo, bFb[0]);
    __builtin_amdgcn_s_setprio(0);
    LGKM0(); SB0();
    VMC(0); SB0();
    BARR();
    LDAf2(1, 0, aLo); LDBf2(1, bFb[1]);
    __builtin_amdgcn_s_setprio(1); MMAC2(1, aHi, bFb[0]);
    __builtin_amdgcn_s_setprio(0);
    LDAf2(1, 1, aHi);
    __builtin_amdgcn_s_setprio(1); MMAC2(0, aLo, bFb[1]);
    __builtin_amdgcn_s_setprio(0);
    __builtin_amdgcn_s_setprio(1); MMAC2(1, aHi, bFb[1]);
    __builtin_amdgcn_s_setprio(0);

    // ---- C write ----
#pragma unroll
    for (int n_ = 0; n_ < 2; ++n_) {
        const int col = n0 + wn * 32 + n_ * 16 + l16;
        const float bb = bias[col];
#pragma unroll
        for (int m_ = 0; m_ < 6; ++m_) {
            const int row = m0 + wr * 96 + m_ * 16 + quad * 4;
#pragma unroll
            for (int r = 0; r < 4; ++r)
                out[(size_t)(row + r) * HID + col] = acc[m_][n_][r] + bb;
        }
    }

#undef LDAf2
#undef LDBf2
#undef MMAC2
#undef STAGE8
#undef TILE2
}

// ---------------------------------------------------------------------------
// Fused rotary + windowed attention. One block per (window, head).
// Rope cos/sin come from precomputed tables (prep range 3).
// ---------------------------------------------------------------------------
__global__ __launch_bounds__(256) void attn_win_kernel(
    const __bf16* __restrict__ qkv,   // [2304, 3840]
    const float* __restrict__ cosb,   // [2304, 40]
    const float* __restrict__ sinb,   // [2304, 40]
    __bf16* __restrict__ attn_out)    // [2304, 1280]
{
    const int w = blockIdx.x;
    const int h = blockIdx.y;

    __shared__ __bf16 Qs[64 * 104];  // [t][d], d padded 80->96, stride 104
    __shared__ __bf16 Ks[64 * 104];
    __shared__ __bf16 Vt[80 * 72];   // [d][t], stride 72
    __shared__ __bf16 Ps[64 * 72];   // probs, stride 72

    const int tid = threadIdx.x;

    for (int u = tid; u < 320; u += 256) {
        const int t = u & 63;
        const int p = u >> 6;
        const int tg = w * 64 + t;
        const size_t base = (size_t)tg * QKV_N + h * HD;
        const int d0 = p * 8;

        bf16x8 qa = *(const bf16x8*)(qkv + base + d0);
        bf16x8 qb = *(const bf16x8*)(qkv + base + d0 + 40);
        bf16x8 ka = *(const bf16x8*)(qkv + base + HID + d0);
        bf16x8 kb = *(const bf16x8*)(qkv + base + HID + d0 + 40);
        bf16x8 va = *(const bf16x8*)(qkv + base + 2 * HID + d0);
        bf16x8 vb = *(const bf16x8*)(qkv + base + 2 * HID + d0 + 40);
        float4 c0 = *(const float4*)(cosb + tg * 40 + d0);
        float4 c1 = *(const float4*)(cosb + tg * 40 + d0 + 4);
        float4 s0 = *(const float4*)(sinb + tg * 40 + d0);
        float4 s1 = *(const float4*)(sinb + tg * 40 + d0 + 4);
        const float cs[8] = {c0.x, c0.y, c0.z, c0.w, c1.x, c1.y, c1.z, c1.w};
        const float sn[8] = {s0.x, s0.y, s0.z, s0.w, s1.x, s1.y, s1.z, s1.w};

        bf16x8 qoa, qob, koa, kob;
#pragma unroll
        for (int j = 0; j < 8; ++j) {
            const float q0 = (float)qa[j], q1 = (float)qb[j];
            const float k0 = (float)ka[j], k1 = (float)kb[j];
            qoa[j] = (__bf16)(q0 * cs[j] - q1 * sn[j]);
            qob[j] = (__bf16)(q0 * sn[j] + q1 * cs[j]);
            koa[j] = (__bf16)(k0 * cs[j] - k1 * sn[j]);
            kob[j] = (__bf16)(k0 * sn[j] + k1 * cs[j]);
        }
        *(bf16x8*)(Qs + t * 104 + d0)      = qoa;
        *(bf16x8*)(Qs + t * 104 + d0 + 40) = qob;
        *(bf16x8*)(Ks + t * 104 + d0)      = koa;
        *(bf16x8*)(Ks + t * 104 + d0 + 40) = kob;
#pragma unroll
        for (int j = 0; j < 8; ++j) {
            Vt[(d0 + j) * 72 + t]      = va[j];
            Vt[(d0 + j + 40) * 72 + t] = vb[j];
        }
    }
    for (int idx = tid; idx < 64 * 16; idx += 256) {
        const int t = idx >> 4, d = 80 + (idx & 15);
        Qs[t * 104 + d] = (__bf16)0.f;
        Ks[t * 104 + d] = (__bf16)0.f;
    }
    __syncthreads();

    const int wave = tid >> 6, lane = tid & 63;
    const int quad = lane >> 4, l16 = lane & 15;

    // ---- S = Q K^T ----
    f32x4 sacc[4] = {};
#pragma unroll
    for (int k0 = 0; k0 < 96; k0 += 32) {
        bf16x8 af = *(const bf16x8*)(Qs + (wave * 16 + l16) * 104 + k0 + quad * 8);
#pragma unroll
        for (int ct = 0; ct < 4; ++ct) {
            bf16x8 bf = *(const bf16x8*)(Ks + (ct * 16 + l16) * 104 + k0 + quad * 8);
            sacc[ct] = __builtin_amdgcn_mfma_f32_16x16x32_bf16(af, bf, sacc[ct], 0, 0, 0);
        }
    }

    // ---- in-register softmax over the 16-lane row group ----
    const float scale = 0.11180339887498948f;  // 1/sqrt(80)
#pragma unroll
    for (int r = 0; r < 4; ++r) {
        float m = -1e30f;
#pragma unroll
        for (int ct = 0; ct < 4; ++ct) {
            sacc[ct][r] *= scale;
            m = fmaxf(m, sacc[ct][r]);
        }
        m = fmaxf(m, __shfl_xor(m, 1));
        m = fmaxf(m, __shfl_xor(m, 2));
        m = fmaxf(m, __shfl_xor(m, 4));
        m = fmaxf(m, __shfl_xor(m, 8));
        float e[4], s = 0.f;
#pragma unroll
        for (int ct = 0; ct < 4; ++ct) {
            e[ct] = __expf(sacc[ct][r] - m);
            s += e[ct];
        }
        s += __shfl_xor(s, 1);
        s += __shfl_xor(s, 2);
        s += __shfl_xor(s, 4);
        s += __shfl_xor(s, 8);
        const float inv = 1.0f / s;
        const int row = wave * 16 + quad * 4 + r;
#pragma unroll
        for (int ct = 0; ct < 4; ++ct)
            Ps[row * 72 + ct * 16 + l16] = (__bf16)(e[ct] * inv);
    }
    __syncthreads();

    // ---- O = P V ----
    f32x4 oacc[5] = {};
#pragma unroll
    for (int k0 = 0; k0 < 64; k0 += 32) {
        bf16x8 af = *(const bf16x8*)(Ps + (wave * 16 + l16) * 72 + k0 + quad * 8);
#pragma unroll
        for (int nt = 0; nt < 5; ++nt) {
            bf16x8 bf = *(const bf16x8*)(Vt + (nt * 16 + l16) * 72 + k0 + quad * 8);
            oacc[nt] = __builtin_amdgcn_mfma_f32_16x16x32_bf16(af, bf, oacc[nt], 0, 0, 0);
        }
    }
#pragma unroll
    for (int nt = 0; nt < 5; ++nt) {
        const int d = nt * 16 + l16;
#pragma unroll
        for (int r = 0; r < 4; ++r) {
            const int t = w * 64 + wave * 16 + quad * 4 + r;
            attn_out[(size_t)t * HID + h * HD + d] = (__bf16)oacc[nt][r];
        }
    }
}

// ---------------------------------------------------------------------------
extern "C" void kernel_launch(void* const* d_in, const int* in_sizes, int n_in,
                              void* d_out, int out_size, void* d_ws, size_t ws_size,
                              hipStream_t stream) {
    const float* x    = (const float*)d_in[0];
    const float* rope = (const float*)d_in[1];
    // d_in[2] = cu_window_seqlens (statically: 36 full 64-token windows)
    const float* Wqkv = (const float*)d_in[3];
    const float* bqkv = (const float*)d_in[4];
    const float* Wo   = (const float*)d_in[5];
    const float* bo   = (const float*)d_in[6];
    float* out = (float*)d_out;

    char* ws = (char*)d_ws;
    const size_t szXb = (size_t)T_TOK * HID * 2;
    const size_t szWq = (size_t)QKV_N * HID * 2;
    const size_t szWo = (size_t)HID * HID * 2;
    const size_t szQK = (size_t)T_TOK * QKV_N * 2;
    __bf16* Xb      = (__bf16*)ws;
    __bf16* Wqkv_t  = (__bf16*)(ws + szXb);
    __bf16* Wo_t    = (__bf16*)(ws + szXb + szWq);
    __bf16* qkv_bf  = (__bf16*)(ws + szXb + szWq + szWo);
    float*  cosb    = (float*)(ws + szXb + szWq + szWo + szQK);
    float*  sinb    = cosb + (size_t)T_TOK * 40;
    __bf16* attn_bf = (__bf16*)ws;   // aliases Xb (dead after gemm_qkv)

    prep_kernel<<<NB_CONV + NB_WQKV + NB_WO + NB_ROPE, 256, 0, stream>>>(
        x, Xb, Wqkv, Wqkv_t, Wo, Wo_t, rope, cosb, sinb);

    // 192x192x64 3-buffer pipeline: 240 blocks, 1 barrier/K-tile
    gemm192_kernel<<<dim3(QKV_N / 192, T_TOK / 192), 512, 0, stream>>>(
        Xb, Wqkv_t, bqkv, qkv_bf);

    attn_win_kernel<<<dim3(NWIN, NH), 256, 0, stream>>>(qkv_bf, cosb, sinb, attn_bf);

    // 192x64x64 pipeline: 240 blocks, 2 blocks/CU
    gemm_wo_kernel<<<dim3(HID / 64, T_TOK / 192), 256, 0, stream>>>(
        attn_bf, Wo_t, bo, out);
}